// Round 13
// baseline (1466.335 us; speedup 1.0000x reference)
//
#include <hip/hip_runtime.h>
#include <hip/hip_bf16.h>
#include <hip/hip_fp16.h>
#include <math.h>
#include <stdint.h>

// Problem constants
#define I_DIM 64
#define H_DIM 256
#define NC    10
#define S1    500
#define S2    41
#define BATCH 128
#define ST    (S1 + S2)          // 541
#define F1    (ST * H_DIM)       // 138496
#define KTOT  (I_DIM + H_DIM)    // 320
#define NKK   10                 // K-steps of 32
#define MB    16                 // batch rows per chunk
#define VH_STRIDE 328            // fp16 row stride for [x|h] (320 + 8 pad)

// fc1 split-K params
#define KC   512
#define KCH  32
#define NSLICE ((F1 + KC - 1) / KC)   // 271

typedef _Float16 f16x8 __attribute__((ext_vector_type(8)));
typedef _Float16 f16x4 __attribute__((ext_vector_type(4)));
typedef float    f32x4 __attribute__((ext_vector_type(4)));

__device__ __forceinline__ float sigmoidf(float x) {
    return 1.0f / (1.0f + __expf(-x));
}
__device__ __forceinline__ float tanh_fast(float x) {
    float e = __expf(2.0f * x);
    return 1.0f - 2.0f / (e + 1.0f);
}

// LDS-only barrier: every cross-thread dependency at these sync points lives
// in LDS (vh), so wait lgkmcnt only. This skips __syncthreads' vmcnt(0) drain
// of in-flight hseq stores / MALL sends / x prefetches (none of which are
// consumed by other threads across the barrier) — they retire in background.
// NOTE: contains NO VMEM ops, so the compiler's counted-vmcnt bookkeeping for
// its own loads stays valid (the r9/r10/r12 asm-VMEM lesson).
#define BAR_LDS() do {                                                  \
    __builtin_amdgcn_sched_barrier(0);                                  \
    asm volatile("s_waitcnt lgkmcnt(0)\n\ts_barrier" ::: "memory");     \
    __builtin_amdgcn_sched_barrier(0);                                  \
} while (0)

// ---------------------------------------------------------------------------
// Pack [w_ih | w_hh] (fp32) into MFMA B-fragment order, fp16 (same as r6-r11):
//   Bp[ ((l*NKK + kk)*64 + ntg)*64 + lane ]  (one f16x8 per lane)
//   n = ntg*16 + (lane&15);  k = kk*32 + (lane>>4)*8 + e
// ---------------------------------------------------------------------------
__global__ __launch_bounds__(256) void prep_pack_b(
        const float* __restrict__ wih1, const float* __restrict__ whh1,
        const float* __restrict__ wih2, const float* __restrict__ whh2,
        f16x8* __restrict__ Bp) {
    int gid = blockIdx.x * 256 + threadIdx.x;      // 0..81919
    int lane = gid & 63;
    int frag = gid >> 6;                           // 0..1279
    int ntg  = frag & 63;
    int rest = frag >> 6;                          // 0..19
    int kk   = rest % NKK;
    int l    = rest / NKK;
    const float* wih = l ? wih2 : wih1;
    const float* whh = l ? whh2 : whh1;
    int n  = ntg * 16 + (lane & 15);               // gate row 0..1023
    int k0 = kk * 32 + (lane >> 4) * 8;
    f16x8 v;
    #pragma unroll
    for (int e = 0; e < 8; ++e) {
        int k = k0 + e;
        float f = (k < I_DIM) ? wih[(size_t)n * I_DIM + k]
                              : whh[(size_t)n * H_DIM + (k - I_DIM)];
        v[e] = (_Float16)f;
    }
    Bp[gid] = v;
}

__global__ __launch_bounds__(256) void prep_bias(
        const float* __restrict__ bih1, const float* __restrict__ bhh1,
        const float* __restrict__ bih2, const float* __restrict__ bhh2,
        float* __restrict__ bsum) {
    int gid = blockIdx.x * 256 + threadIdx.x;      // 0..2047
    if (gid >= 2048) return;
    int l = gid >> 10, n = gid & 1023;
    bsum[gid] = l ? (bih2[n] + bhh2[n]) : (bih1[n] + bhh1[n]);
}

#define XLOAD(p) __hip_atomic_load((p), __ATOMIC_RELAXED, __HIP_MEMORY_SCOPE_AGENT)
#define TAG(w)   ((unsigned)((w) >> 32))

// ---------------------------------------------------------------------------
// Pair-split MFMA peephole LSTM, register/AGPR-resident weights, fence-free
// self-validating 64b exchange (tag+payload in one relaxed agent-scope word —
// the r8/r11-proven transport, and the ONLY transport). r13 changes:
//   * LDS-only barriers (BAR_LDS) -> no per-step vmcnt(0) store drains.
//   * two pipelined poll pairs (step-top + mid-PHASE-A), checked oldest-first;
//     tight no-sleep re-poll for 16 rounds, then sleep-paced. All polls are
//     compiler-issued loads -> counted vmcnt waits remain sound.
// ---------------------------------------------------------------------------
template<int HALF>
__device__ __forceinline__ void lstm_body(
        int l, int b0, int T, int toff, int chunk,
        const float* __restrict__ x,
        const float* __restrict__ wci, const float* __restrict__ wcf, const float* __restrict__ wco,
        const f16x8* __restrict__ Bp, const float* __restrict__ bsum,
        float* __restrict__ hseq, unsigned long long* __restrict__ xbuf,
        _Float16 (*vh)[MB][VH_STRIDE]) {
    const int tid  = threadIdx.x;
    const int lane = tid & 63;
    const int wv   = tid >> 6;             // wave 0..7
    const int lr   = lane & 15;            // n-in-tile / batch row for A
    const int lg   = lane >> 4;            // k-group / batch-quad
    const int uw   = 8 * HALF + wv;        // global unit-tile 0..15
    const int u    = uw * 16 + lr;         // global unit 0..255
    const int ul   = 16 * wv + lr;         // unit local to this half 0..127

    // zero vh (h of buf0 must be 0 at t=0; partner region starts as 0)
    for (int i = tid; i < 2 * MB * VH_STRIDE / 2; i += 512) ((int*)vh)[i] = 0;
    __syncthreads();
    // stage x_0 (fp32 -> fp16)
    if (tid < 256) {
        int bb = tid >> 4, k4 = tid & 15;
        float4 v = *(const float4*)(x + ((size_t)(b0 + bb) * T + 0) * I_DIM + 4 * k4);
        f16x4 p = { (_Float16)v.x, (_Float16)v.y, (_Float16)v.z, (_Float16)v.w };
        *(f16x4*)&vh[0][bb][4 * k4] = p;
    }

    // one-time: this block's B-half into registers/AGPRs (40 frags)
    f16x8 wreg[NKK][4];
    #pragma unroll
    for (int kk = 0; kk < NKK; ++kk)
        #pragma unroll
        for (int q = 0; q < 4; ++q)
            wreg[kk][q] = Bp[(((size_t)l * NKK + kk) * 64 + q * 16 + uw) * 64 + lane];

    float biasv[4];
    #pragma unroll
    for (int q = 0; q < 4; ++q) biasv[q] = bsum[l * 1024 + q * 256 + u];
    const float pi = wci[u], pf = wcf[u], po = wco[u];
    float cst[4] = {0.f, 0.f, 0.f, 0.f};

    // exchange buffers
    unsigned long long* xs_send = xbuf + (size_t)(chunk * 2 + HALF) * 1024;
    const unsigned long long* xs_recv = xbuf + (size_t)(chunk * 2 + (1 - HALF)) * 1024;
    // receiver mapping: this thread owns words 2*tid, 2*tid+1
    const int w0i = 2 * tid, w1i = 2 * tid + 1;
    const int pu0 = 128 * (1 - HALF) + (w0i >> 3), pb0 = w0i & 7;
    const int pu1 = 128 * (1 - HALF) + (w1i >> 3), pb1 = w1i & 7;

    int cur = 0;
    __syncthreads();

    for (int t = 0; t < T; ++t) {
        // issue x_{t+1} load early (committed at end of step)
        float4 xn = make_float4(0.f, 0.f, 0.f, 0.f);
        const bool havex = (tid < 256) && (t + 1 < T);
        if (havex)
            xn = *(const float4*)(x + ((size_t)(b0 + (tid >> 4)) * T + (t + 1)) * I_DIM + 4 * (tid & 15));

        // poll set A at step-top (oldest; ~full PHASE A hides its RTT)
        unsigned long long a0 = 0, a1 = 0, b0v = 0, b1v = 0;
        if (t > 0) {
            a0 = XLOAD(&xs_recv[w0i]);
            a1 = XLOAD(&xs_recv[w1i]);
        }
        __builtin_amdgcn_sched_barrier(0);   // pin poll-A issue here

        f32x4 acc[4];
        #pragma unroll
        for (int q = 0; q < 4; ++q)
            acc[q] = (f32x4){biasv[q], biasv[q], biasv[q], biasv[q]};

#define MK(kk) do {                                                                     \
        f16x8 a_ = *(const f16x8*)&vh[cur][lr][(kk) * 32 + lg * 8];                     \
        acc[0] = __builtin_amdgcn_mfma_f32_16x16x32_f16(a_, wreg[kk][0], acc[0], 0,0,0);\
        acc[1] = __builtin_amdgcn_mfma_f32_16x16x32_f16(a_, wreg[kk][1], acc[1], 0,0,0);\
        acc[2] = __builtin_amdgcn_mfma_f32_16x16x32_f16(a_, wreg[kk][2], acc[2], 0,0,0);\
        acc[3] = __builtin_amdgcn_mfma_f32_16x16x32_f16(a_, wreg[kk][3], acc[3], 0,0,0);\
    } while (0)

        // PHASE A part 1: x + first half of own-h
        MK(0); MK(1);
        if constexpr (HALF == 0) { MK(2); MK(3); }
        else                     { MK(6); MK(7); }
        __builtin_amdgcn_sched_barrier(0);
        // poll set B mid-PHASE-A (fresher by ~200-300 cy)
        if (t > 0) {
            b0v = XLOAD(&xs_recv[w0i]);
            b1v = XLOAD(&xs_recv[w1i]);
        }
        __builtin_amdgcn_sched_barrier(0);
        // PHASE A part 2
        if constexpr (HALF == 0) { MK(4); MK(5); }
        else                     { MK(8); MK(9); }

        // consume partner h_{t-1} (skip t=0: zeros already staged)
        if (t > 0) {
            const unsigned ut = (unsigned)t;
            unsigned long long w0, w1;
            if ((TAG(a0) == ut) && (TAG(a1) == ut)) {        // set A hit
                w0 = a0; w1 = a1;
            } else if ((TAG(b0v) == ut) && (TAG(b1v) == ut)) { // set B hit
                w0 = b0v; w1 = b1v;
            } else {                                          // tight re-poll
                int tries = 0;
                do {
                    if (++tries > 16) __builtin_amdgcn_s_sleep(1);
                    w0 = XLOAD(&xs_recv[w0i]);
                    w1 = XLOAD(&xs_recv[w1i]);
                } while ((TAG(w0) != ut) | (TAG(w1) != ut));
            }
            uint32_t d0 = (uint32_t)w0, d1 = (uint32_t)w1;
            vh[cur][2 * pb0 + 0][I_DIM + pu0] = __builtin_bit_cast(_Float16, (uint16_t)d0);
            vh[cur][2 * pb0 + 1][I_DIM + pu0] = __builtin_bit_cast(_Float16, (uint16_t)(d0 >> 16));
            vh[cur][2 * pb1 + 0][I_DIM + pu1] = __builtin_bit_cast(_Float16, (uint16_t)d1);
            vh[cur][2 * pb1 + 1][I_DIM + pu1] = __builtin_bit_cast(_Float16, (uint16_t)(d1 >> 16));
        }
        BAR_LDS();   // partner region of vh[cur] now valid (LDS-only sync)

        // PHASE B: partner h-half
        if constexpr (HALF == 0) { MK(6); MK(7); MK(8); MK(9); }
        else                     { MK(2); MK(3); MK(4); MK(5); }
#undef MK

        // in-lane activation: 4 cells (batch lg*4+r, unit u)
        _Float16 h16[4];
        float hyv[4];
        #pragma unroll
        for (int r = 0; r < 4; ++r) {
            float c  = cst[r];
            float i_ = sigmoidf(acc[0][r] + pi * c);
            float f_ = sigmoidf(acc[1][r] + pf * c);
            float g_ = tanh_fast(acc[2][r]);
            float cy = f_ * c + i_ * g_;
            float o_ = sigmoidf(acc[3][r] + po * cy);
            float hy = o_ * tanh_fast(cy);
            cst[r] = cy;
            hyv[r] = hy;
            h16[r] = (_Float16)hy;
        }
        // send own h-half FIRST (critical path): 2 self-validating words
        {
            unsigned long long tag = ((unsigned long long)(unsigned)(t + 1)) << 32;
            uint32_t d0 = (uint32_t)__builtin_bit_cast(uint16_t, h16[0])
                        | ((uint32_t)__builtin_bit_cast(uint16_t, h16[1]) << 16);
            uint32_t d1 = (uint32_t)__builtin_bit_cast(uint16_t, h16[2])
                        | ((uint32_t)__builtin_bit_cast(uint16_t, h16[3]) << 16);
            __hip_atomic_store(&xs_send[ul * 8 + 2 * lg + 0], d0 | tag,
                               __ATOMIC_RELAXED, __HIP_MEMORY_SCOPE_AGENT);
            __hip_atomic_store(&xs_send[ul * 8 + 2 * lg + 1], d1 | tag,
                               __ATOMIC_RELAXED, __HIP_MEMORY_SCOPE_AGENT);
        }
        __builtin_amdgcn_sched_barrier(0);   // sends must not sink below bookkeeping
        // local bookkeeping
        #pragma unroll
        for (int r = 0; r < 4; ++r) {
            int b = lg * 4 + r;
            vh[cur ^ 1][b][I_DIM + u] = h16[r];
            hseq[((size_t)(b0 + b) * ST + toff + t) * H_DIM + u] = hyv[r];
        }
        // commit x_{t+1}
        if (havex) {
            f16x4 p = { (_Float16)xn.x, (_Float16)xn.y, (_Float16)xn.z, (_Float16)xn.w };
            *(f16x4*)&vh[cur ^ 1][tid >> 4][4 * (tid & 15)] = p;
        }
        BAR_LDS();   // vh[cur^1] own+x complete (LDS-only sync)
        cur ^= 1;
    }
}

__global__ __launch_bounds__(512, 2) void lstm_pair(
        const float* __restrict__ x1, const float* __restrict__ x2,
        const float* __restrict__ wci1, const float* __restrict__ wcf1, const float* __restrict__ wco1,
        const float* __restrict__ wci2, const float* __restrict__ wcf2, const float* __restrict__ wco2,
        const f16x8* __restrict__ Bp, const float* __restrict__ bsum,
        float* __restrict__ hseq, unsigned long long* __restrict__ xbuf) {
    __shared__ __align__(16) _Float16 vh[2][MB][VH_STRIDE];
    const int bid  = blockIdx.x;           // 0..31
    const int xcd  = bid & 7;
    const int half = (bid >> 3) & 1;
    const int chunk = (bid >> 4) * 8 + xcd;    // 0..15
    const int l    = chunk >> 3;
    const int b0   = (chunk & 7) * MB;
    const int T    = l ? S2 : S1;
    const int toff = l ? S1 : 0;
    const float* x   = l ? x2 : x1;
    const float* wci = l ? wci2 : wci1;
    const float* wcf = l ? wcf2 : wcf1;
    const float* wco = l ? wco2 : wco1;
    if (half == 0)
        lstm_body<0>(l, b0, T, toff, chunk, x, wci, wcf, wco, Bp, bsum, hseq, xbuf, vh);
    else
        lstm_body<1>(l, b0, T, toff, chunk, x, wci, wcf, wco, Bp, bsum, hseq, xbuf, vh);
}

// ---------------------------------------------------------------------------
// fc1 split-K partial GEMM (unchanged)
// ---------------------------------------------------------------------------
__global__ __launch_bounds__(256) void fc1_partial(const float* __restrict__ hseq,
                                                   const float* __restrict__ w,
                                                   float* __restrict__ part) {
    const int s  = blockIdx.x;          // 0..NSLICE-1
    const int k0 = s * KC;
    const int kend = (k0 + KC < F1) ? (k0 + KC) : F1;

    __shared__ float As[KCH][129];      // As[k][b]
    __shared__ float Bs[KCH][129];      // Bs[k][j]

    const int tid = threadIdx.x;
    const int tx = tid & 15;            // j block
    const int ty = tid >> 4;            // b block

    float acc[8][8];
    #pragma unroll
    for (int i = 0; i < 8; ++i)
        #pragma unroll
        for (int j = 0; j < 8; ++j) acc[i][j] = 0.f;

    for (int kk = k0; kk < kend; kk += KCH) {
        #pragma unroll
        for (int r = 0; r < 16; ++r) {
            int idx = r * 256 + tid;    // 0..4095
            int row = idx >> 5;
            int k   = idx & 31;
            int gk  = kk + k;
            float av = (gk < F1) ? hseq[(size_t)row * F1 + gk] : 0.f;
            float bv = (gk < F1) ? w[(size_t)row * F1 + gk] : 0.f;
            As[k][row] = av;
            Bs[k][row] = bv;
        }
        __syncthreads();

        #pragma unroll 8
        for (int k = 0; k < KCH; ++k) {
            float av[8], bv[8];
            #pragma unroll
            for (int i = 0; i < 8; ++i) av[i] = As[k][ty * 8 + i];
            #pragma unroll
            for (int j = 0; j < 8; ++j) bv[j] = Bs[k][tx * 8 + j];
            #pragma unroll
            for (int i = 0; i < 8; ++i)
                #pragma unroll
                for (int j = 0; j < 8; ++j)
                    acc[i][j] = fmaf(av[i], bv[j], acc[i][j]);
        }
        __syncthreads();
    }

    float* dst = part + (size_t)s * (BATCH * 128);
    #pragma unroll
    for (int i = 0; i < 8; ++i)
        #pragma unroll
        for (int j = 0; j < 8; ++j)
            dst[(size_t)(ty * 8 + i) * 128 + (tx * 8 + j)] = acc[i][j];
}

__global__ __launch_bounds__(256) void fc1_reduce(const float* __restrict__ part,
                                                  const float* __restrict__ fc1_b,
                                                  float* __restrict__ out1) {
    int flat = blockIdx.x * 256 + threadIdx.x;     // 0..16383
    float sum = 0.f;
    for (int i = 0; i < NSLICE; ++i)
        sum += part[(size_t)i * (BATCH * 128) + flat];
    int j = flat & 127;
    sum += fc1_b[j];
    out1[flat] = fmaxf(sum, 0.f);
}

__global__ __launch_bounds__(128) void fc2_kernel(const float* __restrict__ out1,
                                                  const float* __restrict__ fcw,
                                                  const float* __restrict__ fcb,
                                                  float* __restrict__ out) {
    int b = blockIdx.x;
    __shared__ float ro[128];
    int tid = threadIdx.x;
    ro[tid] = out1[(size_t)b * 128 + tid];
    __syncthreads();
    if (tid < NC) {
        float s = fcb[tid];
        #pragma unroll 8
        for (int j = 0; j < 128; ++j)
            s = fmaf(ro[j], fcw[(size_t)tid * 128 + j], s);
        out[(size_t)b * NC + tid] = s;
    }
}

// ---------------------------------------------------------------------------
extern "C" void kernel_launch(void* const* d_in, const int* in_sizes, int n_in,
                              void* d_out, int out_size, void* d_ws, size_t ws_size,
                              hipStream_t stream) {
    const float* rr_x  = (const float*)d_in[0];
    const float* rr_wv = (const float*)d_in[1];
    const float* w_ih1 = (const float*)d_in[2];
    const float* w_hh1 = (const float*)d_in[3];
    const float* b_ih1 = (const float*)d_in[4];
    const float* b_hh1 = (const float*)d_in[5];
    const float* wci1  = (const float*)d_in[6];
    const float* wcf1  = (const float*)d_in[7];
    const float* wco1  = (const float*)d_in[8];
    const float* w_ih2 = (const float*)d_in[9];
    const float* w_hh2 = (const float*)d_in[10];
    const float* b_ih2 = (const float*)d_in[11];
    const float* b_hh2 = (const float*)d_in[12];
    const float* wci2  = (const float*)d_in[13];
    const float* wcf2  = (const float*)d_in[14];
    const float* wco2  = (const float*)d_in[15];
    const float* fc1_w = (const float*)d_in[16];
    const float* fc1_b = (const float*)d_in[17];
    const float* fc_w  = (const float*)d_in[18];
    const float* fc_b  = (const float*)d_in[19];
    float* out = (float*)d_out;

    char* ws = (char*)d_ws;
    size_t off = 0;
    f16x8* Bp  = (f16x8*)(ws + off);  off += (size_t)2 * NKK * 64 * 64 * sizeof(f16x8); // 1.31 MB
    float* bsum = (float*)(ws + off); off += (size_t)2048 * sizeof(float);
    float* hseq = (float*)(ws + off); off += (size_t)BATCH * F1 * sizeof(float);        // 70.9 MB
    float* part = (float*)(ws + off); off += (size_t)NSLICE * BATCH * 128 * sizeof(float);
    float* out1 = (float*)(ws + off); off += (size_t)BATCH * 128 * sizeof(float);
    unsigned long long* xbuf = (unsigned long long*)(ws + off);
    off += (size_t)32 * 1024 * sizeof(unsigned long long);                              // 256 KB

    prep_pack_b<<<320, 256, 0, stream>>>(w_ih1, w_hh1, w_ih2, w_hh2, Bp);
    prep_bias<<<8, 256, 0, stream>>>(b_ih1, b_hh1, b_ih2, b_hh2, bsum);
    hipMemsetAsync(xbuf, 0, (size_t)32 * 1024 * sizeof(unsigned long long), stream);

    lstm_pair<<<32, 512, 0, stream>>>(rr_x, rr_wv,
                                      wci1, wcf1, wco1, wci2, wcf2, wco2,
                                      Bp, bsum, hseq, xbuf);

    fc1_partial<<<NSLICE, 256, 0, stream>>>(hseq, fc1_w, part);
    fc1_reduce<<<BATCH * 128 / 256, 256, 0, stream>>>(part, fc1_b, out1);
    fc2_kernel<<<BATCH, 128, 0, stream>>>(out1, fc_w, fc_b, out);
}